// Round 10
// baseline (1582.621 us; speedup 1.0000x reference)
//
#include <hip/hip_runtime.h>
#include <math.h>

#define RADIUS 0.05f

// ---------------- Spatial grid parameters ----------------
#define G 64
#define NC (G * G * G)          // 262144 cells
#define BOXLO -5.5f
#define BOXHI 5.5f
#define CELLH (11.0f / G)       // 0.171875 (exact in fp32)
#define INVH (G / 11.0f)
#define LPQ 4                   // lanes cooperating per query

__device__ __forceinline__ int cell_coord(float v) {
    int c = (int)floorf((v - BOXLO) * INVH);
    return min(G - 1, max(0, c));
}

// ---------------- Grid build ----------------
__global__ void hist_kernel(const float* __restrict__ pcd, unsigned int* __restrict__ cnt, int N) {
    int j = blockIdx.x * 256 + threadIdx.x;
    if (j >= N) return;
    int cx = cell_coord(pcd[3 * j + 0]);
    int cy = cell_coord(pcd[3 * j + 1]);
    int cz = cell_coord(pcd[3 * j + 2]);
    atomicAdd(&cnt[(cx * G + cy) * G + cz], 1u);
}

// S1: per-block (256-cell) exclusive scan; meta = {excl, count}; partials[b] = block sum
__global__ void scan1(const unsigned int* __restrict__ cnt, uint2* __restrict__ meta,
                      unsigned int* __restrict__ partials) {
    __shared__ unsigned int s[256];
    int i = blockIdx.x * 256 + threadIdx.x;
    unsigned int v = cnt[i];
    s[threadIdx.x] = v;
    __syncthreads();
    for (int st = 1; st < 256; st <<= 1) {
        unsigned int a = (threadIdx.x >= (unsigned)st) ? s[threadIdx.x - st] : 0u;
        __syncthreads();
        s[threadIdx.x] += a;
        __syncthreads();
    }
    meta[i] = make_uint2(s[threadIdx.x] - v, v);
    if (threadIdx.x == 255) partials[blockIdx.x] = s[255];
}

// S2: single block, exclusive scan of the 1024 block partials
__global__ void scan2(unsigned int* __restrict__ partials) {
    __shared__ unsigned int s[1024];
    int t = threadIdx.x;
    unsigned int v = partials[t];
    s[t] = v;
    __syncthreads();
    for (int st = 1; st < 1024; st <<= 1) {
        unsigned int a = (t >= st) ? s[t - st] : 0u;
        __syncthreads();
        s[t] += a;
        __syncthreads();
    }
    partials[t] = s[t] - v;  // exclusive
}

// S3: add block offsets; init cursor = final cell offset
__global__ void scan3(uint2* __restrict__ meta, unsigned int* __restrict__ cursor,
                      const unsigned int* __restrict__ partials) {
    int i = blockIdx.x * 256 + threadIdx.x;
    unsigned int off = meta[i].x + partials[blockIdx.x];
    meta[i].x = off;
    cursor[i] = off;
}

// Scatter points (cell-sorted) as {-2p, |p|^2}
__global__ void scatter_kernel(const float* __restrict__ pcd, unsigned int* __restrict__ cursor,
                               float4* __restrict__ pps, int N) {
    int j = blockIdx.x * 256 + threadIdx.x;
    if (j >= N) return;
    float p0 = pcd[3 * j + 0];
    float p1 = pcd[3 * j + 1];
    float p2 = pcd[3 * j + 2];
    int c = (cell_coord(p0) * G + cell_coord(p1)) * G + cell_coord(p2);
    unsigned int idx = atomicAdd(&cursor[c], 1u);
    pps[idx] = make_float4(-2.0f * p0, -2.0f * p1, -2.0f * p2,
                           p0 * p0 + p1 * p1 + p2 * p2);
}

// ---------------- Query: expanding-ring 1-NN, 4 lanes per query ----------------
// Stop rule: after scanning Chebyshev rings <= r, any unscanned point is
// >= r*CELLH - ov away (ov = query overhang outside the box). best tracks
// e = |p|^2 - 2 x.p = d^2 - |x|^2, so termination must compare TRUE squared
// distance: best + |x|^2 <= thr^2.  (r9 bug: compared best alone -> early stop.)
__global__ __launch_bounds__(256) void grid_query(const float* __restrict__ x,
                                                  const float* __restrict__ signs,
                                                  const uint2* __restrict__ meta,
                                                  const float4* __restrict__ pps,
                                                  float* __restrict__ out, int M) {
    int gid = blockIdx.x * 256 + threadIdx.x;
    int q = gid >> 2, sub = gid & (LPQ - 1);
    if (q >= M) return;

    float qx = x[3 * q + 0], qy = x[3 * q + 1], qz = x[3 * q + 2];
    int cx = cell_coord(qx), cy = cell_coord(qy), cz = cell_coord(qz);
    float ov = fmaxf(fmaxf(fmaxf(BOXLO - qx, qx - BOXHI), fmaxf(BOXLO - qy, qy - BOXHI)),
                     fmaxf(fmaxf(BOXLO - qz, qz - BOXHI), 0.0f));
    float xs = fmaf(qx, qx, fmaf(qy, qy, qz * qz));  // |x|^2, for the stop rule

    float best = INFINITY;
    for (int r = 0; r <= G; ++r) {
        int visit = 0;
        for (int dz = -r; dz <= r; ++dz) {
            int z = cz + dz;
            if ((unsigned)z >= (unsigned)G) continue;
            bool face_z = (dz == -r || dz == r);
            for (int dy = -r; dy <= r; ++dy) {
                int y = cy + dy;
                if ((unsigned)y >= (unsigned)G) continue;
                bool face = face_z || (dy == -r || dy == r);
                int step = face ? 1 : 2 * r;
                if (step <= 0) step = 1;
                for (int dx = -r; dx <= r; dx += step) {
                    int xx = cx + dx;
                    if ((unsigned)xx >= (unsigned)G) continue;
                    if (((visit++) & (LPQ - 1)) != sub) continue;  // round-robin over 4 lanes
                    uint2 mc = meta[(xx * G + y) * G + z];
                    const float4* p = pps + mc.x;
                    unsigned k = 0;
                    for (; k + 2 <= mc.y; k += 2) {  // 2 loads in flight
                        float4 a = p[k], b = p[k + 1];
                        float ea = fmaf(a.x, qx, fmaf(a.y, qy, fmaf(a.z, qz, a.w)));
                        float eb = fmaf(b.x, qx, fmaf(b.y, qy, fmaf(b.z, qz, b.w)));
                        best = fminf(best, fminf(ea, eb));
                    }
                    if (k < mc.y) {
                        float4 a = p[k];
                        best = fminf(best, fmaf(a.x, qx, fmaf(a.y, qy, fmaf(a.z, qz, a.w))));
                    }
                }
            }
        }
        // group min over the 4 cooperating lanes (uniform branch within group)
        best = fminf(best, __shfl_xor(best, 1));
        best = fminf(best, __shfl_xor(best, 2));
        float thr = r * CELLH - ov;
        if (thr > 0.0f && best + xs <= thr * thr) break;  // compare TRUE d^2
    }

    if (sub == 0) {
        float d = fmaxf(xs + best, 0.0f);
        out[q] = (sqrtf(d) - RADIUS) * signs[q];
    }
}

// ---------------- Brute-force fallback (r7, proven) ----------------
#define QPT 8
#define NSEG 64
typedef float f32x2 __attribute__((ext_vector_type(2)));

__global__ void init_best(unsigned int* __restrict__ best, int M) {
    int i = blockIdx.x * blockDim.x + threadIdx.x;
    if (i < M) best[i] = 0x7F800000u;
}

__global__ void pack_pcd(const float* __restrict__ pcd, float4* __restrict__ pp, int N) {
    int j = blockIdx.x * blockDim.x + threadIdx.x;
    if (j < N) {
        float p0 = pcd[3 * j], p1 = pcd[3 * j + 1], p2 = pcd[3 * j + 2];
        pp[j] = make_float4(-2.0f * p0, -2.0f * p1, -2.0f * p2,
                            p0 * p0 + p1 * p1 + p2 * p2);
    }
}

__global__ __launch_bounds__(256) void nn_min8(const float* __restrict__ x,
                                               const float4* __restrict__ pp,
                                               unsigned int* __restrict__ best,
                                               int M, int N, int seg_len, int qstride) {
    int t = blockIdx.x * 256 + threadIdx.x;
    int j0 = blockIdx.y * seg_len;
    int j1 = j0 + seg_len;
    if (j1 > N) j1 = N;

    int qid[QPT];
    f32x2 X0[4], X1[4], X2[4], E[4];
#pragma unroll
    for (int r = 0; r < 4; ++r) {
        int q0 = t + (2 * r) * qstride;
        int q1 = t + (2 * r + 1) * qstride;
        qid[2 * r] = q0;
        qid[2 * r + 1] = q1;
        bool ok0 = q0 < M, ok1 = q1 < M;
        int b0 = ok0 ? 3 * q0 : 0;
        int b1 = ok1 ? 3 * q1 : 0;
        X0[r] = (f32x2){ok0 ? x[b0 + 0] : 0.f, ok1 ? x[b1 + 0] : 0.f};
        X1[r] = (f32x2){ok0 ? x[b0 + 1] : 0.f, ok1 ? x[b1 + 1] : 0.f};
        X2[r] = (f32x2){ok0 ? x[b0 + 2] : 0.f, ok1 ? x[b1 + 2] : 0.f};
        E[r] = (f32x2){INFINITY, INFINITY};
    }

#pragma unroll 2
    for (int j = j0; j < j1; ++j) {
        float4 p = pp[j];
        f32x2 px2 = {p.x, p.x};
        f32x2 py2 = {p.y, p.y};
        f32x2 pz2 = {p.z, p.z};
        f32x2 w2 = {p.w, p.w};
#pragma unroll
        for (int r = 0; r < 4; ++r) {
            f32x2 d0 = __builtin_elementwise_fma(pz2, X2[r], w2);
            f32x2 d1 = __builtin_elementwise_fma(py2, X1[r], d0);
            f32x2 d2 = __builtin_elementwise_fma(px2, X0[r], d1);
            E[r].x = fminf(E[r].x, d2.x);
            E[r].y = fminf(E[r].y, d2.y);
        }
    }

#pragma unroll
    for (int r = 0; r < 4; ++r) {
        float xs0 = fmaf(X0[r].x, X0[r].x, fmaf(X1[r].x, X1[r].x, X2[r].x * X2[r].x));
        float xs1 = fmaf(X0[r].y, X0[r].y, fmaf(X1[r].y, X1[r].y, X2[r].y * X2[r].y));
        if (qid[2 * r] < M) {
            float d = fmaxf(xs0 + E[r].x, 0.0f);
            atomicMin(best + qid[2 * r], __float_as_uint(d));
        }
        if (qid[2 * r + 1] < M) {
            float d = fmaxf(xs1 + E[r].y, 0.0f);
            atomicMin(best + qid[2 * r + 1], __float_as_uint(d));
        }
    }
}

__global__ void finalize(unsigned int* __restrict__ bits, const float* __restrict__ signs,
                         float* __restrict__ out, int M) {
    int i = blockIdx.x * blockDim.x + threadIdx.x;
    if (i < M) {
        float d = __uint_as_float(bits[i]);
        out[i] = (sqrtf(d) - RADIUS) * signs[i];
    }
}

// ---------------- Launch ----------------
extern "C" void kernel_launch(void* const* d_in, const int* in_sizes, int n_in,
                              void* d_out, int out_size, void* d_ws, size_t ws_size,
                              hipStream_t stream) {
    const float* x = (const float*)d_in[0];
    const float* pcd = (const float*)d_in[1];
    const float* signs = (const float*)d_in[2];
    float* out = (float*)d_out;

    int M = in_sizes[0] / 3;
    int N = in_sizes[1] / 3;

    // ws carve: pps | meta | cnt | cursor | partials
    size_t need = (size_t)N * 16 + (size_t)NC * 8 + (size_t)NC * 4 + (size_t)NC * 4 + 1024 * 4;

    if (ws_size >= need) {
        char* w = (char*)d_ws;
        float4* pps = (float4*)w;              w += (size_t)N * 16;
        uint2* meta = (uint2*)w;               w += (size_t)NC * 8;
        unsigned int* cnt = (unsigned int*)w;  w += (size_t)NC * 4;
        unsigned int* cursor = (unsigned int*)w; w += (size_t)NC * 4;
        unsigned int* partials = (unsigned int*)w;

        hipMemsetAsync(cnt, 0, (size_t)NC * 4, stream);
        hist_kernel<<<(N + 255) / 256, 256, 0, stream>>>(pcd, cnt, N);
        scan1<<<NC / 256, 256, 0, stream>>>(cnt, meta, partials);
        scan2<<<1, 1024, 0, stream>>>(partials);
        scan3<<<NC / 256, 256, 0, stream>>>(meta, cursor, partials);
        scatter_kernel<<<(N + 255) / 256, 256, 0, stream>>>(pcd, cursor, pps, N);
        grid_query<<<((size_t)M * LPQ + 255) / 256, 256, 0, stream>>>(x, signs, meta, pps, out, M);
    } else {
        // Fallback: proven brute-force path (r7)
        float4* pp = (float4*)d_ws;  // N * 16 B
        init_best<<<(M + 255) / 256, 256, 0, stream>>>((unsigned int*)d_out, M);
        pack_pcd<<<(N + 255) / 256, 256, 0, stream>>>(pcd, pp, N);
        int qstride = (M + QPT - 1) / QPT;
        int seg_len = (N + NSEG - 1) / NSEG;
        dim3 grid((qstride + 255) / 256, NSEG);
        nn_min8<<<grid, 256, 0, stream>>>(x, pp, (unsigned int*)d_out, M, N, seg_len, qstride);
        finalize<<<(M + 255) / 256, 256, 0, stream>>>((unsigned int*)d_out, signs, out, M);
    }
}

// Round 14
// 175.765 us; speedup vs baseline: 9.0042x; 9.0042x over previous
//
#include <hip/hip_runtime.h>
#include <math.h>

#define RADIUS 0.05f

// ---------------- Spatial grid parameters ----------------
#define G 64
#define NC (G * G * G)          // 262144 cells
#define BOXLO -5.5f
#define BOXHI 5.5f
#define CELLH (11.0f / G)       // 0.171875 (exact in fp32)
#define INVH (G / 11.0f)
#define R_CAP 2                 // Phase A ring cap: covers NN <= 0.34 (~98-99% of queries)

__device__ __forceinline__ int cell_coord(float v) {
    int c = (int)floorf((v - BOXLO) * INVH);
    return min(G - 1, max(0, c));
}

// ---------------- Grid build ----------------
__global__ void hist_kernel(const float* __restrict__ pcd, unsigned int* __restrict__ cnt, int N) {
    int j = blockIdx.x * 256 + threadIdx.x;
    if (j >= N) return;
    int cx = cell_coord(pcd[3 * j + 0]);
    int cy = cell_coord(pcd[3 * j + 1]);
    int cz = cell_coord(pcd[3 * j + 2]);
    atomicAdd(&cnt[(cx * G + cy) * G + cz], 1u);
}

__global__ void scan1(const unsigned int* __restrict__ cnt, uint2* __restrict__ meta,
                      unsigned int* __restrict__ partials) {
    __shared__ unsigned int s[256];
    int i = blockIdx.x * 256 + threadIdx.x;
    unsigned int v = cnt[i];
    s[threadIdx.x] = v;
    __syncthreads();
    for (int st = 1; st < 256; st <<= 1) {
        unsigned int a = (threadIdx.x >= (unsigned)st) ? s[threadIdx.x - st] : 0u;
        __syncthreads();
        s[threadIdx.x] += a;
        __syncthreads();
    }
    meta[i] = make_uint2(s[threadIdx.x] - v, v);
    if (threadIdx.x == 255) partials[blockIdx.x] = s[255];
}

__global__ void scan2(unsigned int* __restrict__ partials) {
    __shared__ unsigned int s[1024];
    int t = threadIdx.x;
    unsigned int v = partials[t];
    s[t] = v;
    __syncthreads();
    for (int st = 1; st < 1024; st <<= 1) {
        unsigned int a = (t >= st) ? s[t - st] : 0u;
        __syncthreads();
        s[t] += a;
        __syncthreads();
    }
    partials[t] = s[t] - v;  // exclusive
}

__global__ void scan3(uint2* __restrict__ meta, unsigned int* __restrict__ cursor,
                      const unsigned int* __restrict__ partials) {
    int i = blockIdx.x * 256 + threadIdx.x;
    unsigned int off = meta[i].x + partials[blockIdx.x];
    meta[i].x = off;
    cursor[i] = off;
}

__global__ void scatter_kernel(const float* __restrict__ pcd, unsigned int* __restrict__ cursor,
                               float4* __restrict__ pps, int N) {
    int j = blockIdx.x * 256 + threadIdx.x;
    if (j >= N) return;
    float p0 = pcd[3 * j + 0];
    float p1 = pcd[3 * j + 1];
    float p2 = pcd[3 * j + 2];
    int c = (cell_coord(p0) * G + cell_coord(p1)) * G + cell_coord(p2);
    unsigned int idx = atomicAdd(&cursor[c], 1u);
    pps[idx] = make_float4(-2.0f * p0, -2.0f * p1, -2.0f * p2,
                           p0 * p0 + p1 * p1 + p2 * p2);
}

// ---------------- Phase A: ring search, ONE LANE PER QUERY, capped at R_CAP ----
// r10 lesson: round-robin lane-sharing serializes under SIMT (divergent branch,
// 1570 us, VALUBusy 1.5%). Here each lane owns a query -> 64 independent chains
// per wave. Queries not provably resolved by ring R_CAP go to a queue for the
// brute-force Phase B (bounded tail instead of 5000-cell serial scans).
// best tracks e = |p|^2 - 2 x.p = d^2 - |x|^2; stop rule compares best + |x|^2.
__global__ __launch_bounds__(256) void grid_query_a(const float* __restrict__ x,
                                                    const float* __restrict__ signs,
                                                    const uint2* __restrict__ meta,
                                                    const float4* __restrict__ pps,
                                                    float* __restrict__ out,
                                                    unsigned int* __restrict__ qcount,
                                                    unsigned int* __restrict__ queue, int M) {
    int q = blockIdx.x * 256 + threadIdx.x;
    if (q >= M) return;

    float qx = x[3 * q + 0], qy = x[3 * q + 1], qz = x[3 * q + 2];
    int cx = cell_coord(qx), cy = cell_coord(qy), cz = cell_coord(qz);
    float ov = fmaxf(fmaxf(fmaxf(BOXLO - qx, qx - BOXHI), fmaxf(BOXLO - qy, qy - BOXHI)),
                     fmaxf(fmaxf(BOXLO - qz, qz - BOXHI), 0.0f));
    float xs = fmaf(qx, qx, fmaf(qy, qy, qz * qz));

    float best = INFINITY;
    bool resolved = false;
    for (int r = 0; r <= R_CAP; ++r) {
        for (int dz = -r; dz <= r; ++dz) {
            int z = cz + dz;
            if ((unsigned)z >= (unsigned)G) continue;
            bool face_z = (dz == -r || dz == r);
            for (int dy = -r; dy <= r; ++dy) {
                int y = cy + dy;
                if ((unsigned)y >= (unsigned)G) continue;
                bool face = face_z || (dy == -r || dy == r);
                int step = face ? 1 : 2 * r;
                if (step <= 0) step = 1;
                for (int dx = -r; dx <= r; dx += step) {
                    int xx = cx + dx;
                    if ((unsigned)xx >= (unsigned)G) continue;
                    uint2 mc = meta[(xx * G + y) * G + z];
                    const float4* p = pps + mc.x;
                    unsigned k = 0;
                    for (; k + 2 <= mc.y; k += 2) {
                        float4 a = p[k], b = p[k + 1];
                        float ea = fmaf(a.x, qx, fmaf(a.y, qy, fmaf(a.z, qz, a.w)));
                        float eb = fmaf(b.x, qx, fmaf(b.y, qy, fmaf(b.z, qz, b.w)));
                        best = fminf(best, fminf(ea, eb));
                    }
                    if (k < mc.y) {
                        float4 a = p[k];
                        best = fminf(best, fmaf(a.x, qx, fmaf(a.y, qy, fmaf(a.z, qz, a.w))));
                    }
                }
            }
        }
        float thr = r * CELLH - ov;
        if (thr > 0.0f && best + xs <= thr * thr) { resolved = true; break; }
    }

    if (resolved) {
        float d = fmaxf(xs + best, 0.0f);
        out[q] = (sqrtf(d) - RADIUS) * signs[q];
    } else {
        unsigned int idx = atomicAdd(qcount, 1u);
        queue[idx] = (unsigned int)q;
    }
}

// ---------------- Phase B: one wave per queued query, full brute force --------
// Reuses cell-sorted pps (same point set, any order). Coalesced float4 streams,
// 4 accumulators, 64-lane shfl_xor min-reduce. ~N/64 = 512 pts/lane.
__global__ __launch_bounds__(256) void brute_queue(const float* __restrict__ x,
                                                   const float* __restrict__ signs,
                                                   const float4* __restrict__ pps,
                                                   const unsigned int* __restrict__ qcount,
                                                   const unsigned int* __restrict__ queue,
                                                   float* __restrict__ out, int N) {
    int lane = threadIdx.x & 63;
    int gwave = blockIdx.x * 4 + (threadIdx.x >> 6);
    int nwaves = gridDim.x * 4;
    unsigned int count = *qcount;

    for (unsigned int w = gwave; w < count; w += nwaves) {
        int q = (int)queue[w];  // wave-uniform
        float qx = x[3 * q + 0], qy = x[3 * q + 1], qz = x[3 * q + 2];
        float e0 = INFINITY, e1 = INFINITY, e2 = INFINITY, e3 = INFINITY;
        int j = lane;
        for (; j + 192 < N; j += 256) {
            float4 a = pps[j], b = pps[j + 64], c = pps[j + 128], d4 = pps[j + 192];
            e0 = fminf(e0, fmaf(a.x, qx, fmaf(a.y, qy, fmaf(a.z, qz, a.w))));
            e1 = fminf(e1, fmaf(b.x, qx, fmaf(b.y, qy, fmaf(b.z, qz, b.w))));
            e2 = fminf(e2, fmaf(c.x, qx, fmaf(c.y, qy, fmaf(c.z, qz, c.w))));
            e3 = fminf(e3, fmaf(d4.x, qx, fmaf(d4.y, qy, fmaf(d4.z, qz, d4.w))));
        }
        for (; j < N; j += 64) {
            float4 a = pps[j];
            e0 = fminf(e0, fmaf(a.x, qx, fmaf(a.y, qy, fmaf(a.z, qz, a.w))));
        }
        float e = fminf(fminf(e0, e1), fminf(e2, e3));
        e = fminf(e, __shfl_xor(e, 1));
        e = fminf(e, __shfl_xor(e, 2));
        e = fminf(e, __shfl_xor(e, 4));
        e = fminf(e, __shfl_xor(e, 8));
        e = fminf(e, __shfl_xor(e, 16));
        e = fminf(e, __shfl_xor(e, 32));
        if (lane == 0) {
            float xsq = fmaf(qx, qx, fmaf(qy, qy, qz * qz));
            float d = fmaxf(xsq + e, 0.0f);
            out[q] = (sqrtf(d) - RADIUS) * signs[q];
        }
    }
}

// ---------------- Brute-force fallback (r7, proven) ----------------
#define QPT 8
#define NSEG 64
typedef float f32x2 __attribute__((ext_vector_type(2)));

__global__ void init_best(unsigned int* __restrict__ best, int M) {
    int i = blockIdx.x * blockDim.x + threadIdx.x;
    if (i < M) best[i] = 0x7F800000u;
}

__global__ void pack_pcd(const float* __restrict__ pcd, float4* __restrict__ pp, int N) {
    int j = blockIdx.x * blockDim.x + threadIdx.x;
    if (j < N) {
        float p0 = pcd[3 * j], p1 = pcd[3 * j + 1], p2 = pcd[3 * j + 2];
        pp[j] = make_float4(-2.0f * p0, -2.0f * p1, -2.0f * p2,
                            p0 * p0 + p1 * p1 + p2 * p2);
    }
}

__global__ __launch_bounds__(256) void nn_min8(const float* __restrict__ x,
                                               const float4* __restrict__ pp,
                                               unsigned int* __restrict__ best,
                                               int M, int N, int seg_len, int qstride) {
    int t = blockIdx.x * 256 + threadIdx.x;
    int j0 = blockIdx.y * seg_len;
    int j1 = j0 + seg_len;
    if (j1 > N) j1 = N;

    int qid[QPT];
    f32x2 X0[4], X1[4], X2[4], E[4];
#pragma unroll
    for (int r = 0; r < 4; ++r) {
        int q0 = t + (2 * r) * qstride;
        int q1 = t + (2 * r + 1) * qstride;
        qid[2 * r] = q0;
        qid[2 * r + 1] = q1;
        bool ok0 = q0 < M, ok1 = q1 < M;
        int b0 = ok0 ? 3 * q0 : 0;
        int b1 = ok1 ? 3 * q1 : 0;
        X0[r] = (f32x2){ok0 ? x[b0 + 0] : 0.f, ok1 ? x[b1 + 0] : 0.f};
        X1[r] = (f32x2){ok0 ? x[b0 + 1] : 0.f, ok1 ? x[b1 + 1] : 0.f};
        X2[r] = (f32x2){ok0 ? x[b0 + 2] : 0.f, ok1 ? x[b1 + 2] : 0.f};
        E[r] = (f32x2){INFINITY, INFINITY};
    }

#pragma unroll 2
    for (int j = j0; j < j1; ++j) {
        float4 p = pp[j];
        f32x2 px2 = {p.x, p.x};
        f32x2 py2 = {p.y, p.y};
        f32x2 pz2 = {p.z, p.z};
        f32x2 w2 = {p.w, p.w};
#pragma unroll
        for (int r = 0; r < 4; ++r) {
            f32x2 d0 = __builtin_elementwise_fma(pz2, X2[r], w2);
            f32x2 d1 = __builtin_elementwise_fma(py2, X1[r], d0);
            f32x2 d2 = __builtin_elementwise_fma(px2, X0[r], d1);
            E[r].x = fminf(E[r].x, d2.x);
            E[r].y = fminf(E[r].y, d2.y);
        }
    }

#pragma unroll
    for (int r = 0; r < 4; ++r) {
        float xs0 = fmaf(X0[r].x, X0[r].x, fmaf(X1[r].x, X1[r].x, X2[r].x * X2[r].x));
        float xs1 = fmaf(X0[r].y, X0[r].y, fmaf(X1[r].y, X1[r].y, X2[r].y * X2[r].y));
        if (qid[2 * r] < M) {
            float d = fmaxf(xs0 + E[r].x, 0.0f);
            atomicMin(best + qid[2 * r], __float_as_uint(d));
        }
        if (qid[2 * r + 1] < M) {
            float d = fmaxf(xs1 + E[r].y, 0.0f);
            atomicMin(best + qid[2 * r + 1], __float_as_uint(d));
        }
    }
}

__global__ void finalize(unsigned int* __restrict__ bits, const float* __restrict__ signs,
                         float* __restrict__ out, int M) {
    int i = blockIdx.x * blockDim.x + threadIdx.x;
    if (i < M) {
        float d = __uint_as_float(bits[i]);
        out[i] = (sqrtf(d) - RADIUS) * signs[i];
    }
}

// ---------------- Launch ----------------
extern "C" void kernel_launch(void* const* d_in, const int* in_sizes, int n_in,
                              void* d_out, int out_size, void* d_ws, size_t ws_size,
                              hipStream_t stream) {
    const float* x = (const float*)d_in[0];
    const float* pcd = (const float*)d_in[1];
    const float* signs = (const float*)d_in[2];
    float* out = (float*)d_out;

    int M = in_sizes[0] / 3;
    int N = in_sizes[1] / 3;

    // ws carve: pps | meta | cnt(=cursor, reused after scan1) | partials | qcount | queue
    size_t need = (size_t)N * 16 + (size_t)NC * 8 + (size_t)NC * 4 + 4096 + 64 + (size_t)M * 4;

    if (ws_size >= need) {
        char* w = (char*)d_ws;
        float4* pps = (float4*)w;                 w += (size_t)N * 16;
        uint2* meta = (uint2*)w;                  w += (size_t)NC * 8;
        unsigned int* cnt = (unsigned int*)w;     w += (size_t)NC * 4;  // reused as cursor
        unsigned int* partials = (unsigned int*)w; w += 4096;
        unsigned int* qcount = (unsigned int*)w;  w += 64;
        unsigned int* queue = (unsigned int*)w;
        unsigned int* cursor = cnt;  // cnt dead after scan1; scan3 rewrites it as cursor

        hipMemsetAsync(cnt, 0, (size_t)NC * 4, stream);
        hipMemsetAsync(qcount, 0, 4, stream);
        hist_kernel<<<(N + 255) / 256, 256, 0, stream>>>(pcd, cnt, N);
        scan1<<<NC / 256, 256, 0, stream>>>(cnt, meta, partials);
        scan2<<<1, 1024, 0, stream>>>(partials);
        scan3<<<NC / 256, 256, 0, stream>>>(meta, cursor, partials);
        scatter_kernel<<<(N + 255) / 256, 256, 0, stream>>>(pcd, cursor, pps, N);
        grid_query_a<<<(M + 255) / 256, 256, 0, stream>>>(x, signs, meta, pps, out,
                                                          qcount, queue, M);
        brute_queue<<<256, 256, 0, stream>>>(x, signs, pps, qcount, queue, out, N);
    } else {
        // Fallback: proven brute-force path (r7)
        float4* pp = (float4*)d_ws;  // N * 16 B
        init_best<<<(M + 255) / 256, 256, 0, stream>>>((unsigned int*)d_out, M);
        pack_pcd<<<(N + 255) / 256, 256, 0, stream>>>(pcd, pp, N);
        int qstride = (M + QPT - 1) / QPT;
        int seg_len = (N + NSEG - 1) / NSEG;
        dim3 grid((qstride + 255) / 256, NSEG);
        nn_min8<<<grid, 256, 0, stream>>>(x, pp, (unsigned int*)d_out, M, N, seg_len, qstride);
        finalize<<<(M + 255) / 256, 256, 0, stream>>>((unsigned int*)d_out, signs, out, M);
    }
}